// Round 6
// baseline (176.560 us; speedup 1.0000x reference)
//
#include <hip/hip_runtime.h>
#include <hip/hip_bf16.h>
#include <hip/hip_fp16.h>

#define FEAT 2048
#define NCLS 751
#define NPAD 768
#define NPRB 64
#define NGAL 256
#define WSCALE 256.0f

typedef _Float16 f16x8 __attribute__((ext_vector_type(8)));
typedef float f32x4 __attribute__((ext_vector_type(4)));

__device__ __forceinline__ unsigned short f2h_u(float x) {
  union { _Float16 h; unsigned short u; } v;
  v.h = (_Float16)x;
  return v.u;
}

// ---------------------------------------------------------------------------
// Kernel 1: per-feature moments -> BN scale s[f], shift t[f].
// 256 blocks x (8 features x 32 row-lanes).
// mean[f] = M2p - 2 M1p M1g + M2g ; E[d^2] = M4p - 4M3p M1g + 6M2p M2g - 4M1p M3g + M4g
// ---------------------------------------------------------------------------
__global__ __launch_bounds__(256)
void stats_kernel(const float* __restrict__ P, const float* __restrict__ G,
                  const float* __restrict__ gamma, const float* __restrict__ beta,
                  float* __restrict__ st) {
  const int t = threadIdx.x;
  const int fx = t & 7, ry = t >> 3;          // 8 features x 32 row-lanes
  const int f = blockIdx.x * 8 + fx;
  float a1 = 0, a2 = 0, a3 = 0, a4 = 0;
#pragma unroll
  for (int r = ry; r < NPRB; r += 32) {       // 2 iters
    float x = P[r * FEAT + f], x2 = x * x;
    a1 += x; a2 += x2; a3 += x2 * x; a4 += x2 * x2;
  }
  float b1 = 0, b2 = 0, b3 = 0, b4 = 0;
#pragma unroll
  for (int r = ry; r < NGAL; r += 32) {       // 8 iters
    float x = G[r * FEAT + f], x2 = x * x;
    b1 += x; b2 += x2; b3 += x2 * x; b4 += x2 * x2;
  }
  __shared__ float red[8][32][8];   // [moment][ry][fx]
  __shared__ float red2[8][4][8];   // [moment][quarter][fx]
  float vals[8] = {a1, a2, a3, a4, b1, b2, b3, b4};
#pragma unroll
  for (int m = 0; m < 8; ++m) red[m][ry][fx] = vals[m];
  __syncthreads();
  {
    int m = t >> 5, q = (t >> 3) & 3, fx2 = t & 7;
    float s = 0.f;
#pragma unroll
    for (int r = 0; r < 8; ++r) s += red[m][q * 8 + r][fx2];
    red2[m][q][fx2] = s;
  }
  __syncthreads();
  if (t < 8) {
    float mm[8];
#pragma unroll
    for (int m = 0; m < 8; ++m)
      mm[m] = red2[m][0][t] + red2[m][1][t] + red2[m][2][t] + red2[m][3][t];
    float M1p = mm[0] * (1.f / NPRB), M2p = mm[1] * (1.f / NPRB);
    float M3p = mm[2] * (1.f / NPRB), M4p = mm[3] * (1.f / NPRB);
    float M1g = mm[4] * (1.f / NGAL), M2g = mm[5] * (1.f / NGAL);
    float M3g = mm[6] * (1.f / NGAL), M4g = mm[7] * (1.f / NGAL);
    float mean = M2p - 2.f * M1p * M1g + M2g;
    float Ed2 = M4p - 4.f * M3p * M1g + 6.f * M2p * M2g - 4.f * M1p * M3g + M4g;
    float var = Ed2 - mean * mean;
    int ff = blockIdx.x * 8 + t;
    float sv = gamma[ff] / sqrtf(var + 1e-5f);
    st[ff] = sv;
    st[FEAT + ff] = beta[ff] - mean * sv;  // t[f]
  }
}

// ---------------------------------------------------------------------------
// Kernel 2 (fused): per class c:
//   Wp[c,f] = W[c,f] * s[f] * WSCALE (f16), bp[c] = b[c] + sum_f t[f] W[c,f]
// ---------------------------------------------------------------------------
__global__ void prepw_kernel(const float* __restrict__ W, const float* __restrict__ b,
                             const float* __restrict__ st,
                             unsigned short* __restrict__ Wp, float* __restrict__ bp) {
  int c = blockIdx.x;
  int f = threadIdx.x * 8;
  float4 w0 = make_float4(0.f, 0.f, 0.f, 0.f), w1 = w0;
  if (c < NCLS) {
    const float4* wsrc = (const float4*)(W + (size_t)c * FEAT + f);
    w0 = wsrc[0]; w1 = wsrc[1];
  }
  const float4* s4 = (const float4*)(st + f);
  float4 s0 = s4[0], s1 = s4[1];
  const float4* t4 = (const float4*)(st + FEAT + f);
  float4 t0 = t4[0], t1 = t4[1];
  uint4 u;
  u.x = (unsigned int)f2h_u(w0.x * s0.x * WSCALE) | ((unsigned int)f2h_u(w0.y * s0.y * WSCALE) << 16);
  u.y = (unsigned int)f2h_u(w0.z * s0.z * WSCALE) | ((unsigned int)f2h_u(w0.w * s0.w * WSCALE) << 16);
  u.z = (unsigned int)f2h_u(w1.x * s1.x * WSCALE) | ((unsigned int)f2h_u(w1.y * s1.y * WSCALE) << 16);
  u.w = (unsigned int)f2h_u(w1.z * s1.z * WSCALE) | ((unsigned int)f2h_u(w1.w * s1.w * WSCALE) << 16);
  *(uint4*)(Wp + (size_t)c * FEAT + f) = u;
  float acc = t0.x * w0.x + t0.y * w0.y + t0.z * w0.z + t0.w * w0.w +
              t1.x * w1.x + t1.y * w1.y + t1.z * w1.z + t1.w * w1.w;
#pragma unroll
  for (int off = 32; off > 0; off >>= 1) acc += __shfl_down(acc, off, 64);
  __shared__ float r[4];
  int wave = threadIdx.x >> 6, lane = threadIdx.x & 63;
  if (lane == 0) r[wave] = acc;
  __syncthreads();
  if (threadIdx.x == 0) bp[c] = (c < NCLS ? b[c] : 0.f) + r[0] + r[1] + r[2] + r[3];
}

// ---------------------------------------------------------------------------
// Kernel 3 (fused GEMM): out = BN((P-G)^2) @ W'^T + b'.
// M=16384, N=768, K=2048. Tile 128x192, BK=64, 512 threads (8 waves, wave
// tile 64x48, acc[4][3]). Grid 128x4 = 512 blocks = exactly 2 blk/CU.
// Round-5 lesson: all pipes <25% busy, weak response to +1 wave -> the wall
// is the per-barrier vmcnt(0) drain: read set (Wp 3MB + G 2MB) > 4MB L2, so
// some loads are L3 (~600-900cy) but were issued only ~300-400cy before the
// drain. Fix: BK=64 doubles work per barrier (24 MFMA/wave), halves barrier
// count (32), and puts B(t+1) glds in flight top->end (~1200+cy) and G/P
// consumption after 24 MFMAs -- latency fully covered. LDS 80KB keeps the
// occupancy at 2 blk/CU (grid exactly 2/CU), avoiding the m132 failure mode.
// 128B LDS rows restore the full-row swizzle slot = chunk ^ (row&7)
// (round-0/1-verified, 0 conflicts): A-write 8-lane groups cover all 32
// banks; B glds source chunk (tid&7)^((tid>>3)&7) is instr-independent
// (i*64 == 0 mod 8); frag reads have row&7 == frow&7 (wm,wn == 0 mod 8).
// ---------------------------------------------------------------------------
__global__ __launch_bounds__(512, 4)
void gemm_fused_kernel(const float* __restrict__ P, const float* __restrict__ G,
                       const unsigned short* __restrict__ Wp,
                       const float* __restrict__ bp, float* __restrict__ out) {
  __shared__ unsigned short As[2][128 * 64];  // 2 x 16 KB
  __shared__ unsigned short Bs[2][192 * 64];  // 2 x 24 KB  (80 KB total)

  const int tid = threadIdx.x;
  const int lane = tid & 63, wave = tid >> 6;  // 8 waves
  const int mtile = blockIdx.x, ntile = blockIdx.y;
  const int p = mtile >> 1;

  // A-gen roles: thread -> row = tid>>2 (0..127), chunks ac0, ac0+1 (64B).
  const int arow = tid >> 2, ac0 = (tid & 3) * 2;
  const int aslot = ac0 ^ (arow & 7);  // even; second write at aslot^1
  unsigned short* aw0;                 // set per-buffer below
  const float* gp = G + (size_t)((mtile & 1) * 128 + arow) * FEAT + ac0 * 8;
  const float* pp = P + (size_t)p * FEAT + ac0 * 8;  // L1-broadcast source

  // B staging: 3 glds insts; inst i covers dest idx i*512+tid ->
  // row = i*64 + (tid>>3), slot = tid&7, source chunk = (tid&7)^((tid>>3)&7).
  const int bch = (tid & 7) ^ ((tid >> 3) & 7);
  const unsigned short* bg =
      Wp + (size_t)(ntile * 192 + (tid >> 3)) * FEAT + bch * 8;
  const int bdo = wave * 1024;  // + i*8192; HW adds lane*16

  // ---- prologue: tile 0 ----
  float4 g0, g1, g2, g3, p0, p1, p2, p3;
  g0 = ((const float4*)gp)[0]; g1 = ((const float4*)gp)[1];
  g2 = ((const float4*)gp)[2]; g3 = ((const float4*)gp)[3];
  p0 = ((const float4*)pp)[0]; p1 = ((const float4*)pp)[1];
  p2 = ((const float4*)pp)[2]; p3 = ((const float4*)pp)[3];
#pragma unroll
  for (int i = 0; i < 3; ++i)
    __builtin_amdgcn_global_load_lds(
        (const __attribute__((address_space(1))) void*)(bg + (size_t)i * 64 * FEAT),
        (__attribute__((address_space(3))) void*)((char*)Bs[0] + i * 8192 + bdo), 16, 0, 0);
  {  // A(0) -> As[0]
    float d0 = p0.x - g0.x, d1 = p0.y - g0.y, d2 = p0.z - g0.z, d3 = p0.w - g0.w;
    float d4 = p1.x - g1.x, d5 = p1.y - g1.y, d6 = p1.z - g1.z, d7 = p1.w - g1.w;
    float e0 = p2.x - g2.x, e1 = p2.y - g2.y, e2 = p2.z - g2.z, e3 = p2.w - g2.w;
    float e4 = p3.x - g3.x, e5 = p3.y - g3.y, e6 = p3.z - g3.z, e7 = p3.w - g3.w;
    uint4 ua, ub;
    ua.x = (unsigned int)f2h_u(d0 * d0) | ((unsigned int)f2h_u(d1 * d1) << 16);
    ua.y = (unsigned int)f2h_u(d2 * d2) | ((unsigned int)f2h_u(d3 * d3) << 16);
    ua.z = (unsigned int)f2h_u(d4 * d4) | ((unsigned int)f2h_u(d5 * d5) << 16);
    ua.w = (unsigned int)f2h_u(d6 * d6) | ((unsigned int)f2h_u(d7 * d7) << 16);
    ub.x = (unsigned int)f2h_u(e0 * e0) | ((unsigned int)f2h_u(e1 * e1) << 16);
    ub.y = (unsigned int)f2h_u(e2 * e2) | ((unsigned int)f2h_u(e3 * e3) << 16);
    ub.z = (unsigned int)f2h_u(e4 * e4) | ((unsigned int)f2h_u(e5 * e5) << 16);
    ub.w = (unsigned int)f2h_u(e6 * e6) | ((unsigned int)f2h_u(e7 * e7) << 16);
    unsigned short* ab = As[0] + arow * 64;
    *(uint4*)(ab + aslot * 8) = ua;
    *(uint4*)(ab + (aslot ^ 1) * 8) = ub;
  }
  __syncthreads();  // A(0) visible; B(0) drained (vmcnt0 at barrier)

  f32x4 acc[4][3];
#pragma unroll
  for (int mi = 0; mi < 4; ++mi)
#pragma unroll
    for (int ni = 0; ni < 3; ++ni) acc[mi][ni] = (f32x4){0.f, 0.f, 0.f, 0.f};

  const int wm = (wave & 1) * 64, wn = (wave >> 1) * 48;
  const int frow = lane & 15, fk = lane >> 4;

  // ---- main loop: 32 K-steps (BK=64), one barrier each ----
  int cur = 0;
  for (int t = 0; t < 32; ++t) {
    const int k0 = t * 64;
    const bool hn = (t < 31);

    if (hn) {
      // 1. G/P(t+1) -> regs (consumed in phase 4, after 24 MFMAs)
      const float* gn = gp + k0 + 64;
      const float* pn = pp + k0 + 64;
      g0 = ((const float4*)gn)[0]; g1 = ((const float4*)gn)[1];
      g2 = ((const float4*)gn)[2]; g3 = ((const float4*)gn)[3];
      p0 = ((const float4*)pn)[0]; p1 = ((const float4*)pn)[1];
      p2 = ((const float4*)pn)[2]; p3 = ((const float4*)pn)[3];
      // 2. B(t+1) -> Bs[cur^1] (in flight for the whole iteration)
#pragma unroll
      for (int i = 0; i < 3; ++i)
        __builtin_amdgcn_global_load_lds(
            (const __attribute__((address_space(1))) void*)(bg + k0 + 64 + (size_t)i * 64 * FEAT),
            (__attribute__((address_space(3))) void*)((char*)Bs[cur ^ 1] + i * 8192 + bdo), 16, 0, 0);
    }

    // 3. fragments + MFMA on buffer `cur`: 2 k-phases x 12 MFMA
    __builtin_amdgcn_s_setprio(1);
#pragma unroll
    for (int kk = 0; kk < 2; ++kk) {
      const int fslot = (kk * 4 + fk) ^ (frow & 7);
      f16x8 af[4], bf[3];
#pragma unroll
      for (int mi = 0; mi < 4; ++mi)
        af[mi] = *(const f16x8*)(As[cur] + (wm + mi * 16 + frow) * 64 + fslot * 8);
#pragma unroll
      for (int ni = 0; ni < 3; ++ni)
        bf[ni] = *(const f16x8*)(Bs[cur] + (wn + ni * 16 + frow) * 64 + fslot * 8);
#pragma unroll
      for (int mi = 0; mi < 4; ++mi)
#pragma unroll
        for (int ni = 0; ni < 3; ++ni)
          acc[mi][ni] = __builtin_amdgcn_mfma_f32_16x16x32_f16(af[mi], bf[ni], acc[mi][ni], 0, 0, 0);
    }
    __builtin_amdgcn_s_setprio(0);

    // 4. A-gen(t+1) -> As[cur^1] (G/P vmcnt drains here, ~24 MFMAs later)
    if (hn) {
      float d0 = p0.x - g0.x, d1 = p0.y - g0.y, d2 = p0.z - g0.z, d3 = p0.w - g0.w;
      float d4 = p1.x - g1.x, d5 = p1.y - g1.y, d6 = p1.z - g1.z, d7 = p1.w - g1.w;
      float e0 = p2.x - g2.x, e1 = p2.y - g2.y, e2 = p2.z - g2.z, e3 = p2.w - g2.w;
      float e4 = p3.x - g3.x, e5 = p3.y - g3.y, e6 = p3.z - g3.z, e7 = p3.w - g3.w;
      uint4 ua, ub;
      ua.x = (unsigned int)f2h_u(d0 * d0) | ((unsigned int)f2h_u(d1 * d1) << 16);
      ua.y = (unsigned int)f2h_u(d2 * d2) | ((unsigned int)f2h_u(d3 * d3) << 16);
      ua.z = (unsigned int)f2h_u(d4 * d4) | ((unsigned int)f2h_u(d5 * d5) << 16);
      ua.w = (unsigned int)f2h_u(d6 * d6) | ((unsigned int)f2h_u(d7 * d7) << 16);
      ub.x = (unsigned int)f2h_u(e0 * e0) | ((unsigned int)f2h_u(e1 * e1) << 16);
      ub.y = (unsigned int)f2h_u(e2 * e2) | ((unsigned int)f2h_u(e3 * e3) << 16);
      ub.z = (unsigned int)f2h_u(e4 * e4) | ((unsigned int)f2h_u(e5 * e5) << 16);
      ub.w = (unsigned int)f2h_u(e6 * e6) | ((unsigned int)f2h_u(e7 * e7) << 16);
      unsigned short* ab = As[cur ^ 1] + arow * 64;
      *(uint4*)(ab + aslot * 8) = ua;
      *(uint4*)(ab + (aslot ^ 1) * 8) = ub;
    }

    __syncthreads();  // single drain point: B(t+1) landed, A(t+1) visible
    cur ^= 1;
  }

  // epilogue: C/D layout col=lane&15, row=(lane>>4)*4+reg; undo WSCALE, add b'
  const int col0 = ntile * 192 + wn + (lane & 15);
  const int row0 = mtile * 128 + wm + ((lane >> 4) << 2);
#pragma unroll
  for (int ni = 0; ni < 3; ++ni) {
    int col = col0 + ni * 16;
    if (col >= NCLS) continue;
    float bv = bp[col];
#pragma unroll
    for (int mi = 0; mi < 4; ++mi) {
      int row = row0 + mi * 16;
#pragma unroll
      for (int r = 0; r < 4; ++r)
        out[(size_t)(row + r) * NCLS + col] = acc[mi][ni][r] * (1.0f / WSCALE) + bv;
    }
  }
}

// ---------------------------------------------------------------------------
extern "C" void kernel_launch(void* const* d_in, const int* in_sizes, int n_in,
                              void* d_out, int out_size, void* d_ws, size_t ws_size,
                              hipStream_t stream) {
  const float* P = (const float*)d_in[0];
  const float* G = (const float*)d_in[1];
  const float* gamma = (const float*)d_in[2];
  const float* beta = (const float*)d_in[3];
  const float* W = (const float*)d_in[4];
  const float* b = (const float*)d_in[5];
  float* out = (float*)d_out;

  float* st = (float*)d_ws;                           // s[2048], t[2048]
  float* bp = st + 2 * FEAT;                          // b'[768]
  unsigned short* Wp = (unsigned short*)(bp + NPAD);  // f16 W' [768, 2048]

  hipLaunchKernelGGL(stats_kernel, dim3(256), dim3(256), 0, stream, P, G, gamma, beta, st);
  hipLaunchKernelGGL(prepw_kernel, dim3(NPAD), dim3(256), 0, stream, W, b, st, Wp, bp);
  hipLaunchKernelGGL(gemm_fused_kernel, dim3(128, 4), dim3(512), 0, stream, P, G, Wp, bp, out);
}